// Round 2
// baseline (16493.303 us; speedup 1.0000x reference)
//
#include <hip/hip_runtime.h>

#define TT 2048
#define BATCH 512
#define DIMK 25
#define LAYERS 10
#define NC 7

__device__ __forceinline__ float sigm(float z) {
  // 1 / (1 + exp(-z))
  return __builtin_amdgcn_rcpf(1.0f + __expf(-z));
}

// 512 blocks (one batch element each), 2 blocks/CU for stall overlap.
// __launch_bounds__(512,4): min 4 waves/SIMD -> VGPR cap 128 -> both blocks
// stay resident (129+ VGPRs would halve waves/SIMD and kill the overlap).
__launch_bounds__(512, 4)
__global__ void lstm_fused(const float* __restrict__ x,
                           const float* __restrict__ h0,
                           const float* __restrict__ c0,
                           const float* __restrict__ Wih,
                           const float* __restrict__ Whh,
                           const float* __restrict__ bias,
                           const float* __restrict__ fcw,
                           const float* __restrict__ fcb,
                           float* __restrict__ out) {
  // slot 0 = x(t), slot l+1 = h_l. 32-float (128B) stride: float4-aligned.
  __shared__ __align__(16) float buf[LAYERS + 1][32];
  __shared__ __align__(16) float gbuf[LAYERS][100];  // only f(25..49), o(75..99) used
  __shared__ __align__(16) float h9p[2][32];         // parity-buffered layer-9 h
  __shared__ __align__(16) float fcw_s[NC][28];      // FC weights in LDS (keeps VGPR<=128)
  __shared__ float fcb_s[NC];
  __shared__ float eb[8];                            // FC exp staging (wave-7 local)

  const int tid = threadIdx.x;
  const int b0 = blockIdx.x;       // one batch element per block
  const int l = tid / 50;          // 0..9 compute layers; >=10 for tid>=500
  const int u = tid % 50;
  const bool comp = (tid < 500);
  const int lcl = comp ? l : 9;

  // Resident per-thread weights: gate rows r1=u (i or f), r2=u+50 (g or o)
  float wih1[DIMK], wih2[DIMK], whh1[DIMK], whh2[DIMK];
  float bias1 = 0.f, bias2 = 0.f;
  float c = 0.f;                   // cell state for unit u (u<25)

  const bool isfc = (tid >= 500) && (tid < 500 + NC);  // tid 500..506, wave 7
  const int fccls = tid - 500;

  if (comp) {
    const int r1 = u, r2 = u + 50;
    const float* wi1 = Wih + (l * 100 + r1) * DIMK;
    const float* wi2 = Wih + (l * 100 + r2) * DIMK;
    const float* wh1 = Whh + (l * 100 + r1) * DIMK;
    const float* wh2 = Whh + (l * 100 + r2) * DIMK;
#pragma unroll
    for (int k = 0; k < DIMK; ++k) {
      wih1[k] = wi1[k]; wih2[k] = wi2[k];
      whh1[k] = wh1[k]; whh2[k] = wh2[k];
    }
    bias1 = bias[l * 100 + r1];
    bias2 = bias[l * 100 + r2];
    if (u < 25) {
      c = c0[(l * BATCH + b0) * DIMK + u];
      buf[l + 1][u] = h0[(l * BATCH + b0) * DIMK + u];
    }
    if (l == 0 && u >= 25) {
      buf[0][u - 25] = x[(size_t)b0 * DIMK + (u - 25)];  // x(t=0)
    }
  }
  if (isfc) {
#pragma unroll
    for (int k = 0; k < DIMK; ++k) fcw_s[fccls][k] = fcw[fccls * DIMK + k];
    fcw_s[fccls][25] = 0.f; fcw_s[fccls][26] = 0.f; fcw_s[fccls][27] = 0.f;
    fcb_s[fccls] = fcb[fccls];
  }
  if (tid == 507) {  // zero h9p pads so padded float4 FC dot is clean
#pragma unroll
    for (int p = 0; p < 2; ++p)
      for (int k = 25; k < 32; ++k) h9p[p][k] = 0.f;
  }
  __syncthreads();

  // r2 activation: tanh for u<25 (g gate), sigmoid for u>=25 (o gate).
  const float s2 = (u < 25) ? 2.0f : 1.0f;
  const float s2m1 = s2 - 1.0f;

  const float* inp = &buf[lcl][0];
  float* own = &buf[lcl + 1][0];

  float g1 = 0.f, g2 = 0.f;
  float xpre = 0.f;

  for (int s = 0; s < TT + LAYERS; ++s) {
    const int t = s - l;
    const bool act = comp && ((unsigned)t < (unsigned)TT);

    // x(t+1) prefetch issue (layer-0 f/o threads; latency hides under phase 1)
    if (comp && l == 0 && u >= 25 && (s + 1) < TT) {
      xpre = x[((size_t)(s + 1) * BATCH + b0) * DIMK + (u - 25)];
    }

    if (act) {
      // ---- phase 1: 2 gate preactivations = 2 dots of 50
      float ai1 = 0.f, ai2 = 0.f, ah1 = 0.f, ah2 = 0.f;
#pragma unroll
      for (int kk = 0; kk < 24; kk += 4) {
        const float4 vi = *(const float4*)(inp + kk);
        const float4 vh = *(const float4*)(own + kk);
        ai1 += wih1[kk+0]*vi.x; ai1 += wih1[kk+1]*vi.y; ai1 += wih1[kk+2]*vi.z; ai1 += wih1[kk+3]*vi.w;
        ai2 += wih2[kk+0]*vi.x; ai2 += wih2[kk+1]*vi.y; ai2 += wih2[kk+2]*vi.z; ai2 += wih2[kk+3]*vi.w;
        ah1 += whh1[kk+0]*vh.x; ah1 += whh1[kk+1]*vh.y; ah1 += whh1[kk+2]*vh.z; ah1 += whh1[kk+3]*vh.w;
        ah2 += whh2[kk+0]*vh.x; ah2 += whh2[kk+1]*vh.y; ah2 += whh2[kk+2]*vh.z; ah2 += whh2[kk+3]*vh.w;
      }
      const float vi24 = inp[24], vh24 = own[24];
      const float a1 = bias1 + ai1 + ah1 + wih1[24]*vi24 + whh1[24]*vh24;
      const float a2 = bias2 + ai2 + ah2 + wih2[24]*vi24 + whh2[24]*vh24;

      g1 = sigm(a1);                      // i (u<25) or f (u>=25)
      g2 = s2 * sigm(s2 * a2) - s2m1;     // tanh->g (u<25) or sigmoid->o

      if (u >= 25) {                      // publish f and o; i,g stay in regs
        gbuf[l][u]      = g1;
        gbuf[l][u + 50] = g2;
      }
    }
    __syncthreads();

    // ---- phase 2: cell/hidden update on unit threads (u<25)
    if (act && u < 25) {
      const float f = gbuf[l][u + 25], o = gbuf[l][u + 75];
      c = f * c + g1 * g2;                               // f*c + i*g
      const float tc = 2.0f * sigm(2.0f * c) - 1.0f;     // tanh(c)
      const float h = o * tc;
      own[u] = h;
      if (l == 9) h9p[s & 1][u] = h;
    }
    // x prefetch commit (layer-0 f/o threads, idle in phase 2)
    if (comp && l == 0 && u >= 25 && (s + 1) < TT) {
      buf[0][u - 25] = xpre;
    }
    // FC + softmax on spare threads (tid 500..506), one step behind h9
    if (isfc) {
      const int tf = s - 10;
      if ((unsigned)tf < (unsigned)TT) {
        const float* hp = &h9p[(s + 1) & 1][0];  // parity of step s-1
        const float* fw = &fcw_s[fccls][0];
        float acc = fcb_s[fccls];
#pragma unroll
        for (int kk = 0; kk < 28; kk += 4) {     // pads are zeroed
          const float4 v = *(const float4*)(hp + kk);
          const float4 w = *(const float4*)(fw + kk);
          acc += w.x*v.x; acc += w.y*v.y; acc += w.z*v.z; acc += w.w*v.w;
        }
        // |logit| small; no max-subtraction needed
        const float e = __expf(acc);
        eb[fccls] = e;   // all 7 FC lanes in wave 7: in-order LDS, no barrier
        const float ssum = eb[0] + eb[1] + eb[2] + eb[3] + eb[4] + eb[5] + eb[6];
        out[((size_t)tf * BATCH + b0) * NC + fccls] =
            e * __builtin_amdgcn_rcpf(ssum);
      }
    }
    __syncthreads();
  }
}

extern "C" void kernel_launch(void* const* d_in, const int* in_sizes, int n_in,
                              void* d_out, int out_size, void* d_ws, size_t ws_size,
                              hipStream_t stream) {
  const float* x   = (const float*)d_in[0];
  const float* h0  = (const float*)d_in[1];
  const float* c0  = (const float*)d_in[2];
  const float* Wih = (const float*)d_in[3];
  const float* Whh = (const float*)d_in[4];
  const float* b   = (const float*)d_in[5];
  const float* fcw = (const float*)d_in[6];
  const float* fcb = (const float*)d_in[7];
  float* out = (float*)d_out;

  lstm_fused<<<dim3(512), dim3(512), 0, stream>>>(x, h0, c0, Wih, Whh, b, fcw,
                                                  fcb, out);
}

// Round 3
// 5054.334 us; speedup vs baseline: 3.2632x; 3.2632x over previous
//
#include <hip/hip_runtime.h>

#define TT 2048
#define BATCH 512
#define DIMK 25
#define LAYERS 10
#define NC 7

__device__ __forceinline__ float sigm(float z) {
  // 1 / (1 + exp(-z))
  return __builtin_amdgcn_rcpf(1.0f + __expf(-z));
}

// 512 blocks (one batch element each), 2 blocks/CU for stall overlap.
// NOTE (measured R1/R2): on this compiler the 2nd __launch_bounds__ arg acts
// as min BLOCKS/CU: (512,2)->128 VGPR cap (no spill, R1-verified fit),
// (512,4)->64 VGPR cap (spilled 100-float weight arrays -> 50GB scratch
// traffic, 16.5ms). Keep it at 2.
__launch_bounds__(512, 2)
__global__ void lstm_fused(const float* __restrict__ x,
                           const float* __restrict__ h0,
                           const float* __restrict__ c0,
                           const float* __restrict__ Wih,
                           const float* __restrict__ Whh,
                           const float* __restrict__ bias,
                           const float* __restrict__ fcw,
                           const float* __restrict__ fcb,
                           float* __restrict__ out) {
  // slot 0 = x(t), slot l+1 = h_l. 32-float (128B) stride: float4-aligned.
  __shared__ __align__(16) float buf[LAYERS + 1][32];
  __shared__ __align__(16) float gbuf[LAYERS][100];  // only f(25..49), o(75..99) used
  __shared__ __align__(16) float h9p[2][32];         // parity-buffered layer-9 h
  __shared__ __align__(16) float fcw_s[NC][28];      // FC weights in LDS (keeps VGPR<=128)
  __shared__ float fcb_s[NC];
  __shared__ float eb[8];                            // FC exp staging (wave-7 local)

  const int tid = threadIdx.x;
  const int b0 = blockIdx.x;       // one batch element per block
  const int l = tid / 50;          // 0..9 compute layers; >=10 for tid>=500
  const int u = tid % 50;
  const bool comp = (tid < 500);
  const int lcl = comp ? l : 9;

  // Resident per-thread weights: gate rows r1=u (i or f), r2=u+50 (g or o)
  float wih1[DIMK], wih2[DIMK], whh1[DIMK], whh2[DIMK];
  float bias1 = 0.f, bias2 = 0.f;
  float c = 0.f;                   // cell state for unit u (u<25)

  const bool isfc = (tid >= 500) && (tid < 500 + NC);  // tid 500..506, wave 7
  const int fccls = tid - 500;

  if (comp) {
    const int r1 = u, r2 = u + 50;
    const float* wi1 = Wih + (l * 100 + r1) * DIMK;
    const float* wi2 = Wih + (l * 100 + r2) * DIMK;
    const float* wh1 = Whh + (l * 100 + r1) * DIMK;
    const float* wh2 = Whh + (l * 100 + r2) * DIMK;
#pragma unroll
    for (int k = 0; k < DIMK; ++k) {
      wih1[k] = wi1[k]; wih2[k] = wi2[k];
      whh1[k] = wh1[k]; whh2[k] = wh2[k];
    }
    bias1 = bias[l * 100 + r1];
    bias2 = bias[l * 100 + r2];
    if (u < 25) {
      c = c0[(l * BATCH + b0) * DIMK + u];
      buf[l + 1][u] = h0[(l * BATCH + b0) * DIMK + u];
    }
    if (l == 0 && u >= 25) {
      buf[0][u - 25] = x[(size_t)b0 * DIMK + (u - 25)];  // x(t=0)
    }
  }
  if (isfc) {
#pragma unroll
    for (int k = 0; k < DIMK; ++k) fcw_s[fccls][k] = fcw[fccls * DIMK + k];
    fcw_s[fccls][25] = 0.f; fcw_s[fccls][26] = 0.f; fcw_s[fccls][27] = 0.f;
    fcb_s[fccls] = fcb[fccls];
  }
  if (tid == 507) {  // zero h9p pads so padded float4 FC dot is clean
#pragma unroll
    for (int p = 0; p < 2; ++p)
      for (int k = 25; k < 32; ++k) h9p[p][k] = 0.f;
  }
  __syncthreads();

  // r2 activation: tanh for u<25 (g gate), sigmoid for u>=25 (o gate).
  const float s2 = (u < 25) ? 2.0f : 1.0f;
  const float s2m1 = s2 - 1.0f;

  const float* inp = &buf[lcl][0];
  float* own = &buf[lcl + 1][0];

  float g1 = 0.f, g2 = 0.f;
  float xpre = 0.f;

  for (int s = 0; s < TT + LAYERS; ++s) {
    const int t = s - l;
    const bool act = comp && ((unsigned)t < (unsigned)TT);

    // x(t+1) prefetch issue (layer-0 f/o threads; latency hides under phase 1)
    if (comp && l == 0 && u >= 25 && (s + 1) < TT) {
      xpre = x[((size_t)(s + 1) * BATCH + b0) * DIMK + (u - 25)];
    }

    if (act) {
      // ---- phase 1: 2 gate preactivations = 2 dots of 50
      float ai1 = 0.f, ai2 = 0.f, ah1 = 0.f, ah2 = 0.f;
#pragma unroll
      for (int kk = 0; kk < 24; kk += 4) {
        const float4 vi = *(const float4*)(inp + kk);
        const float4 vh = *(const float4*)(own + kk);
        ai1 += wih1[kk+0]*vi.x; ai1 += wih1[kk+1]*vi.y; ai1 += wih1[kk+2]*vi.z; ai1 += wih1[kk+3]*vi.w;
        ai2 += wih2[kk+0]*vi.x; ai2 += wih2[kk+1]*vi.y; ai2 += wih2[kk+2]*vi.z; ai2 += wih2[kk+3]*vi.w;
        ah1 += whh1[kk+0]*vh.x; ah1 += whh1[kk+1]*vh.y; ah1 += whh1[kk+2]*vh.z; ah1 += whh1[kk+3]*vh.w;
        ah2 += whh2[kk+0]*vh.x; ah2 += whh2[kk+1]*vh.y; ah2 += whh2[kk+2]*vh.z; ah2 += whh2[kk+3]*vh.w;
      }
      const float vi24 = inp[24], vh24 = own[24];
      const float a1 = bias1 + ai1 + ah1 + wih1[24]*vi24 + whh1[24]*vh24;
      const float a2 = bias2 + ai2 + ah2 + wih2[24]*vi24 + whh2[24]*vh24;

      g1 = sigm(a1);                      // i (u<25) or f (u>=25)
      g2 = s2 * sigm(s2 * a2) - s2m1;     // tanh->g (u<25) or sigmoid->o

      if (u >= 25) {                      // publish f and o; i,g stay in regs
        gbuf[l][u]      = g1;
        gbuf[l][u + 50] = g2;
      }
    }
    __syncthreads();

    // ---- phase 2: cell/hidden update on unit threads (u<25)
    if (act && u < 25) {
      const float f = gbuf[l][u + 25], o = gbuf[l][u + 75];
      c = f * c + g1 * g2;                               // f*c + i*g
      const float tc = 2.0f * sigm(2.0f * c) - 1.0f;     // tanh(c)
      const float h = o * tc;
      own[u] = h;
      if (l == 9) h9p[s & 1][u] = h;
    }
    // x prefetch commit (layer-0 f/o threads, idle in phase 2)
    if (comp && l == 0 && u >= 25 && (s + 1) < TT) {
      buf[0][u - 25] = xpre;
    }
    // FC + softmax on spare threads (tid 500..506), one step behind h9
    if (isfc) {
      const int tf = s - 10;
      if ((unsigned)tf < (unsigned)TT) {
        const float* hp = &h9p[(s + 1) & 1][0];  // parity of step s-1
        const float* fw = &fcw_s[fccls][0];
        float acc = fcb_s[fccls];
#pragma unroll
        for (int kk = 0; kk < 28; kk += 4) {     // pads are zeroed
          const float4 v = *(const float4*)(hp + kk);
          const float4 w = *(const float4*)(fw + kk);
          acc += w.x*v.x; acc += w.y*v.y; acc += w.z*v.z; acc += w.w*v.w;
        }
        // |logit| small; no max-subtraction needed
        const float e = __expf(acc);
        eb[fccls] = e;   // all 7 FC lanes in wave 7: in-order LDS, no barrier
        const float ssum = eb[0] + eb[1] + eb[2] + eb[3] + eb[4] + eb[5] + eb[6];
        out[((size_t)tf * BATCH + b0) * NC + fccls] =
            e * __builtin_amdgcn_rcpf(ssum);
      }
    }
    __syncthreads();
  }
}

extern "C" void kernel_launch(void* const* d_in, const int* in_sizes, int n_in,
                              void* d_out, int out_size, void* d_ws, size_t ws_size,
                              hipStream_t stream) {
  const float* x   = (const float*)d_in[0];
  const float* h0  = (const float*)d_in[1];
  const float* c0  = (const float*)d_in[2];
  const float* Wih = (const float*)d_in[3];
  const float* Whh = (const float*)d_in[4];
  const float* b   = (const float*)d_in[5];
  const float* fcw = (const float*)d_in[6];
  const float* fcb = (const float*)d_in[7];
  float* out = (float*)d_out;

  lstm_fused<<<dim3(512), dim3(512), 0, stream>>>(x, h0, c0, Wih, Whh, b, fcw,
                                                  fcb, out);
}

// Round 4
// 4140.416 us; speedup vs baseline: 3.9835x; 1.2207x over previous
//
#include <hip/hip_runtime.h>

#define TT 2048
#define BQ 512
#define LAYERS 10
#define NC 7

__device__ __forceinline__ float sigm(float z) {
  return __builtin_amdgcn_rcpf(1.0f + __expf(-z));
}
// readlane -> wave-uniform value (compiler keeps it in an SGPR)
__device__ __forceinline__ float rl(float v, int k) {
  return __int_as_float(__builtin_amdgcn_readlane(__float_as_int(v), k));
}

// Layer-per-wave pipelined LSTM. Block = 10 waves (wave l = layer l), 2 batch
// elements per block, grid 256 => 1 block/CU, single round over all CUs.
// h broadcast: own-h via v_readlane->SGPR (VALU), input-h via LDS broadcast
// reads. f/o exchange intra-wave via __shfl. ONE barrier per step.
// NOTE (measured R1/R2/R3): 2nd __launch_bounds__ arg acts as min BLOCKS/CU:
// (x,2)->128 VGPR cap, (x,4)->64 (spill disaster). (640,1) -> cap ~168,
// 10 waves/CU either way.
__launch_bounds__(640, 1)
__global__ void lstm_fused(const float* __restrict__ x,
                           const float* __restrict__ h0,
                           const float* __restrict__ c0,
                           const float* __restrict__ Wih,
                           const float* __restrict__ Whh,
                           const float* __restrict__ bias,
                           const float* __restrict__ fcw,
                           const float* __restrict__ fcb,
                           float* __restrict__ out) {
  // hs[parity][l][.]: input vector for wave l (batch A at 0..24, B at 32..56).
  // Written by wave l-1 (its h) at parity s&1; read at parity (s&1)^1.
  // Slot [*][0] is wave-0-private x staging.
  __shared__ __align__(16) float hs[2][LAYERS + 1][64];
  __shared__ float eb[16];  // wave-9-local softmax exp staging

  const int tid = threadIdx.x;
  const int l = tid >> 6;          // wave index = layer (0..9)
  const int lane = tid & 63;
  const int bA = 2 * blockIdx.x;   // batch pair for this block
  const bool isA = lane < 25;
  const bool on = lane < 50;       // LSTM compute lanes
  const int u = isA ? lane : lane - 25;   // unit 0..24 (junk for lane>=50)
  const int r1 = isA ? u : u + 25;        // row: i_u (A-lanes) or f_u (B-lanes)

  float w_i1[25], w_i2[25], w_h1[25], w_h2[25];
  float b1 = 0.f, b2 = 0.f, c = 0.f, h = 0.f;

  const bool isfc = (l == 9) && (lane >= 50);  // 14 lanes: (class, batch)
  const int j = lane - 50;                     // 0..13
  const int fcls = j % NC;
  const int fbat = j / NC;                     // 0=A, 1=B

  if (on) {
    const float* pi1 = Wih + (l * 100 + r1) * 25;
    const float* ph1 = Whh + (l * 100 + r1) * 25;
#pragma unroll
    for (int k = 0; k < 25; ++k) {
      w_i1[k] = pi1[k];        w_i2[k] = pi1[50 * 25 + k];
      w_h1[k] = ph1[k];        w_h2[k] = ph1[50 * 25 + k];
    }
    b1 = bias[l * 100 + r1];
    b2 = bias[l * 100 + r1 + 50];
    const int bb = bA + (isA ? 0 : 1);
    c = c0[(l * BQ + bb) * 25 + u];
    h = h0[(l * BQ + bb) * 25 + u];
  } else if (isfc) {
    // FC weights overlay the (unused) w_h1 slots of wave 9's upper lanes.
#pragma unroll
    for (int k = 0; k < 25; ++k) w_h1[k] = fcw[fcls * 25 + k];
    b1 = fcb[fcls];
  }

  // own-h scalars (SGPRs): shA[k] = h_A^k (lane k), shB[k] = h_B^k (lane k+25)
  float shA[25], shB[25];
#pragma unroll
  for (int k = 0; k < 25; ++k) { shA[k] = rl(h, k); shB[k] = rl(h, k + 25); }

  const float s2 = isA ? 2.0f : 1.0f;   // g-gate tanh via 2*sigm(2z)-1
  const float s2m1 = s2 - 1.0f;

  for (int s = 0; s < TT + LAYERS; ++s) {
    // ---- FC + softmax for t = s-10 on wave 9 lanes 50..63.
    // Uses shA/shB from the END of step s-1 == h9(s-10). Must run BEFORE
    // this step's readlane update.
    if (l == 9 && s >= LAYERS) {
      if (lane >= 50) {
        float acc = b1;
#pragma unroll
        for (int k = 0; k < 25; ++k) acc += w_h1[k] * (fbat ? shB[k] : shA[k]);
        const float e = __expf(acc);   // logits are small; no max-subtract
        eb[j] = e;                     // same-wave LDS: ordered by lgkmcnt
        const float* ebb = eb + fbat * NC;
        const float ssum = ebb[0] + ebb[1] + ebb[2] + ebb[3] + ebb[4] + ebb[5] + ebb[6];
        out[((size_t)(s - LAYERS) * BQ + bA + fbat) * NC + fcls] =
            e * __builtin_amdgcn_rcpf(ssum);
      }
    }

    const int t = s - l;
    if ((unsigned)t < (unsigned)TT) {   // wave-uniform predicate
      const int pr = (s & 1) ^ 1;       // read parity (written last step)

      if (l == 0) {
        // Stage x(t) into our private input slot; same-wave write->read is
        // ordered by lgkmcnt, no barrier needed.
        if (on) {
          const float xv = x[((size_t)t * BQ + bA) * 25 + lane];  // 50 contig
          hs[pr][0][isA ? u : 32 + u] = xv;
        }
      }

      const float* rp = &hs[pr][l][0];
      float a_i1A = b1, a_i2A = b2, a_h1A = 0.f, a_h2A = 0.f;
      float a_i1B = b1, a_i2B = b2, a_h1B = 0.f, a_h2B = 0.f;
#pragma unroll
      for (int k = 0; k < 25; ++k) {
        const float vA = rp[k];        // LDS broadcast (merges to b128)
        const float vB = rp[32 + k];
        a_i1A += w_i1[k] * vA;  a_i2A += w_i2[k] * vA;
        a_i1B += w_i1[k] * vB;  a_i2B += w_i2[k] * vB;
        a_h1A += w_h1[k] * shA[k];  a_h2A += w_h2[k] * shA[k];  // v_fmac v,s,v
        a_h1B += w_h1[k] * shB[k];  a_h2B += w_h2[k] * shB[k];
      }
      const float a1A = a_i1A + a_h1A;
      const float a2A = a_i2A + a_h2A;
      const float a1B = a_i1B + a_h1B;
      const float a2B = a_i2B + a_h2B;

      const float g1A = sigm(a1A);                   // i (A-lanes) / f (B-lanes)
      const float g2A = s2 * sigm(s2 * a2A) - s2m1;  // tanh g / sigm o
      const float g1B = sigm(a1B);
      const float g2B = s2 * sigm(s2 * a2B) - s2m1;

      // Swap with partner lane (u <-> u+25): A-lanes receive f/o of batch A,
      // B-lanes receive i/g of batch B.
      const int partner = isA ? lane + 25 : lane - 25;
      const float q1 = __shfl(isA ? g1B : g1A, partner);
      const float q2 = __shfl(isA ? g2B : g2A, partner);

      const float iG = isA ? g1A : q1;
      const float gG = isA ? g2A : q2;
      const float fG = isA ? q1 : g1B;
      const float oG = isA ? q2 : g2B;
      c = fG * c + iG * gG;
      const float th = 2.0f * sigm(2.0f * c) - 1.0f;  // tanh(c)
      h = oG * th;

      if (on && l < 9) hs[s & 1][l + 1][isA ? u : 32 + u] = h;  // handoff

      // refresh own-h SGPRs for next step (and FC at s+1 for wave 9)
#pragma unroll
      for (int k = 0; k < 25; ++k) { shA[k] = rl(h, k); shB[k] = rl(h, k + 25); }
    }
    __syncthreads();  // the ONE barrier per step
  }
}

extern "C" void kernel_launch(void* const* d_in, const int* in_sizes, int n_in,
                              void* d_out, int out_size, void* d_ws, size_t ws_size,
                              hipStream_t stream) {
  const float* x   = (const float*)d_in[0];
  const float* h0  = (const float*)d_in[1];
  const float* c0  = (const float*)d_in[2];
  const float* Wih = (const float*)d_in[3];
  const float* Whh = (const float*)d_in[4];
  const float* b   = (const float*)d_in[5];
  const float* fcw = (const float*)d_in[6];
  const float* fcb = (const float*)d_in[7];
  float* out = (float*)d_out;

  lstm_fused<<<dim3(256), dim3(640), 0, stream>>>(x, h0, c0, Wih, Whh, b, fcw,
                                                  fcb, out);
}

// Round 5
// 3703.165 us; speedup vs baseline: 4.4538x; 1.1181x over previous
//
#include <hip/hip_runtime.h>

#define TT 2048
#define BQ 512
#define LAYERS 10
#define NC 7

__device__ __forceinline__ float sigm(float z) {
  return __builtin_amdgcn_rcpf(1.0f + __expf(-z));
}

// Wave-per-layer pipelined LSTM, R5.
// Block = 11 waves (704 thr): waves 0..9 = layers, wave 10 = FC+softmax+store.
// 2 batch elements per block, grid 256 = 1 block/CU.
// Lane layout (compute waves): lane = 2u+g, u=0..24, g in {0,1}.
//   g=0: gate rows i_u, g_u (both batches) + owns (u, batch A) c/h state.
//   g=1: gate rows f_u, o_u (both batches) + owns (u, batch B) c/h state.
// Gate exchange: __shfl_xor(.,1) -> DPP quad_perm (VALU, no LDS pipe).
// All h broadcast through LDS slots: wave l reads hs[pr][l] (input) and
// hs[pr][l+1] (own h, written by itself last step), writes hs[s&1][l+1].
// ONE barrier per step. x prefetched one step ahead in registers.
// NOTE (measured R1/R2): 2nd __launch_bounds__ arg = min blocks/CU here;
// (704,1) -> 11 waves/CU -> 3 waves/SIMD -> ~170-reg budget, no spill.
__launch_bounds__(704, 1)
__global__ void lstm_fused(const float* __restrict__ x,
                           const float* __restrict__ h0,
                           const float* __restrict__ c0,
                           const float* __restrict__ Wih,
                           const float* __restrict__ Whh,
                           const float* __restrict__ bias,
                           const float* __restrict__ fcw,
                           const float* __restrict__ fcb,
                           float* __restrict__ out) {
  // hs[parity][slot][.]: batch A at [0..24], batch B at [32..56].
  // slot 0 = x staging; slot l+1 = h of layer l.
  __shared__ __align__(16) float hs[2][LAYERS + 2][64];
  __shared__ float eb[16];  // FC-wave softmax exp staging

  const int tid = threadIdx.x;
  const int w = tid >> 6;          // wave index: 0..9 layers, 10 FC
  const int lane = tid & 63;
  const int bA = 2 * blockIdx.x;
  const bool comp = (w < LAYERS) && (lane < 50);
  const int g = lane & 1;          // 0: i,g rows + batch A; 1: f,o rows + batch B
  const int u = lane >> 1;         // unit 0..24

  float wi1[25], wi2[25], wh1[25], wh2[25];
  float b1 = 0.f, b2 = 0.f, c = 0.f;
  float xpre = 0.f;

  const bool isfc = (w == LAYERS) && (lane < 14);
  const int fcls = lane % NC;      // class
  const int fbat = lane / NC;      // 0=A, 1=B (junk for lane>=14)

  if (comp) {
    const int r1 = g ? (u + 25) : u;        // f_u : i_u
    const int r2 = g ? (u + 75) : (u + 50); // o_u : g_u
    const float* pi1 = Wih + (w * 100 + r1) * 25;
    const float* pi2 = Wih + (w * 100 + r2) * 25;
    const float* ph1 = Whh + (w * 100 + r1) * 25;
    const float* ph2 = Whh + (w * 100 + r2) * 25;
#pragma unroll
    for (int k = 0; k < 25; ++k) {
      wi1[k] = pi1[k]; wi2[k] = pi2[k];
      wh1[k] = ph1[k]; wh2[k] = ph2[k];
    }
    b1 = bias[w * 100 + r1];
    b2 = bias[w * 100 + r2];
    const int bb = bA + g;                   // this lane's owned batch elem
    c = c0[(w * BQ + bb) * 25 + u];
    const float h00 = h0[(w * BQ + bb) * 25 + u];
    const int idx = g ? (32 + u) : u;
    hs[0][w + 1][idx] = h00;                 // both parities: first own-h read
    hs[1][w + 1][idx] = h00;                 // parity depends on layer parity
  } else if (isfc) {
#pragma unroll
    for (int k = 0; k < 25; ++k) wi1[k] = fcw[fcls * 25 + k];
    b1 = fcb[fcls];
  }
  if (w == 0 && lane < 50) {
    xpre = x[(size_t)bA * 25 + lane];        // x(t=0), 50 contiguous floats
  }
  __syncthreads();

  const float s2 = g ? 1.0f : 2.0f;          // gate2: tanh (g) vs sigm (o)
  const float s2m1 = s2 - 1.0f;

  for (int s = 0; s < TT + LAYERS; ++s) {
    const int pr = (s & 1) ^ 1;              // read parity

    if (w < LAYERS) {
      const int t = s - w;                   // wave-uniform
      if ((unsigned)t < (unsigned)TT) {
        if (w == 0) {
          if (lane < 50) {
            // stage x(t) from prefetch reg; same-wave write->read ordered
            hs[pr][0][lane < 25 ? lane : lane + 7] = xpre;  // 32+(lane-25)
            if (s + 1 < TT)
              xpre = x[((size_t)(s + 1) * BQ + bA) * 25 + lane];
          }
        }
        if (lane < 50) {
          const float* ip = &hs[pr][w][0];       // input h (or x)
          const float* op = &hs[pr][w + 1][0];   // own h (self-written)
          float a1A = b1, a2A = b2, a1B = b1, a2B = b2;
          float h1A = 0.f, h2A = 0.f, h1B = 0.f, h2B = 0.f;
#pragma unroll
          for (int k = 0; k < 24; k += 4) {
            const float4 viA = *(const float4*)(ip + k);
            const float4 viB = *(const float4*)(ip + 32 + k);
            const float4 vhA = *(const float4*)(op + k);
            const float4 vhB = *(const float4*)(op + 32 + k);
            a1A += wi1[k+0]*viA.x; a1A += wi1[k+1]*viA.y; a1A += wi1[k+2]*viA.z; a1A += wi1[k+3]*viA.w;
            a2A += wi2[k+0]*viA.x; a2A += wi2[k+1]*viA.y; a2A += wi2[k+2]*viA.z; a2A += wi2[k+3]*viA.w;
            a1B += wi1[k+0]*viB.x; a1B += wi1[k+1]*viB.y; a1B += wi1[k+2]*viB.z; a1B += wi1[k+3]*viB.w;
            a2B += wi2[k+0]*viB.x; a2B += wi2[k+1]*viB.y; a2B += wi2[k+2]*viB.z; a2B += wi2[k+3]*viB.w;
            h1A += wh1[k+0]*vhA.x; h1A += wh1[k+1]*vhA.y; h1A += wh1[k+2]*vhA.z; h1A += wh1[k+3]*vhA.w;
            h2A += wh2[k+0]*vhA.x; h2A += wh2[k+1]*vhA.y; h2A += wh2[k+2]*vhA.z; h2A += wh2[k+3]*vhA.w;
            h1B += wh1[k+0]*vhB.x; h1B += wh1[k+1]*vhB.y; h1B += wh1[k+2]*vhB.z; h1B += wh1[k+3]*vhB.w;
            h2B += wh2[k+0]*vhB.x; h2B += wh2[k+1]*vhB.y; h2B += wh2[k+2]*vhB.z; h2B += wh2[k+3]*vhB.w;
          }
          {
            const float viA = ip[24], viB = ip[32 + 24];
            const float vhA = op[24], vhB = op[32 + 24];
            a1A += wi1[24]*viA; a2A += wi2[24]*viA;
            a1B += wi1[24]*viB; a2B += wi2[24]*viB;
            h1A += wh1[24]*vhA; h2A += wh2[24]*vhA;
            h1B += wh1[24]*vhB; h2B += wh2[24]*vhB;
          }
          const float p1A = a1A + h1A, p2A = a2A + h2A;
          const float p1B = a1B + h1B, p2B = a2B + h2B;

          const float G1A = sigm(p1A);                   // i_A (g=0) / f_A (g=1)
          const float G1B = sigm(p1B);
          const float G2A = s2 * sigm(s2 * p2A) - s2m1;  // g_A tanh / o_A sigm
          const float G2B = s2 * sigm(s2 * p2B) - s2m1;

          // exchange with lane^1 (DPP quad_perm): g=0 sends B-pair, gets (fA,oA);
          // g=1 sends A-pair, gets (iB,gB).
          const float q1 = __shfl_xor(g ? G1A : G1B, 1);
          const float q2 = __shfl_xor(g ? G2A : G2B, 1);

          const float iG = g ? q1 : G1A;
          const float gg = g ? q2 : G2A;
          const float fG = g ? G1B : q1;
          const float oG = g ? G2B : q2;
          c = fG * c + iG * gg;
          const float th = 2.0f * sigm(2.0f * c) - 1.0f;  // tanh(c)
          const float h = oG * th;
          hs[s & 1][w + 1][g ? (32 + u) : u] = h;
        }
      }
    } else {
      // ---- FC + softmax wave: t = s-10, reads h9 written last step
      const int t = s - LAYERS;
      if ((unsigned)t < (unsigned)TT && lane < 14) {
        const float* hp = &hs[pr][LAYERS][fbat * 32];
        float acc = b1;
#pragma unroll
        for (int k = 0; k < 24; k += 4) {
          const float4 v = *(const float4*)(hp + k);
          acc += wi1[k+0]*v.x; acc += wi1[k+1]*v.y; acc += wi1[k+2]*v.z; acc += wi1[k+3]*v.w;
        }
        acc += wi1[24] * hp[24];
        const float e = __expf(acc);           // logits small; no max-subtract
        eb[lane] = e;                          // same-wave LDS, lgkmcnt-ordered
        const float* ebb = eb + fbat * NC;
        const float ssum = ebb[0] + ebb[1] + ebb[2] + ebb[3] + ebb[4] + ebb[5] + ebb[6];
        out[((size_t)t * BQ + bA + fbat) * NC + fcls] =
            e * __builtin_amdgcn_rcpf(ssum);
      }
    }
    __syncthreads();  // the ONE barrier per step
  }
}

extern "C" void kernel_launch(void* const* d_in, const int* in_sizes, int n_in,
                              void* d_out, int out_size, void* d_ws, size_t ws_size,
                              hipStream_t stream) {
  const float* x   = (const float*)d_in[0];
  const float* h0  = (const float*)d_in[1];
  const float* c0  = (const float*)d_in[2];
  const float* Wih = (const float*)d_in[3];
  const float* Whh = (const float*)d_in[4];
  const float* b   = (const float*)d_in[5];
  const float* fcw = (const float*)d_in[6];
  const float* fcb = (const float*)d_in[7];
  float* out = (float*)d_out;

  lstm_fused<<<dim3(256), dim3(704), 0, stream>>>(x, h0, c0, Wih, Whh, b, fcw,
                                                  fcb, out);
}